// Round 12
// baseline (113.644 us; speedup 1.0000x reference)
//
#include <hip/hip_runtime.h>

// SoftDiceLoss: predictions [B=8, C=16, H=512, W=512] fp32, targets [B,H,W] int32.
// out[b] = -(1/C) * sum_c (2*overlap[b,c] + 1) / (i_sum[b,c] + count[b,c] + 1)
//
// Fused single kernel. Main loop is R7's VERBATIM (best measured: 28.8 us):
//   512 blocks = (8 batches x 64 slabs of 4096 pos) x 256 thr, bounds(256,8);
//   tpack u64 nibble-packed targets; 16 class segments streamed sequentially
//   as 4-deep float4 bursts; 5-VALU exact nibble==c mask; in-loop DPP wave
//   reduce (pure VALU) -> LDS -> partial[comp][block].
// Appended tail (R11-proven mechanics): device-fence + atomic counter
//   (memset to 0 each launch -> deterministic, graph-safe); last-done block
//   DPP-reduces the 48x512 partials and writes out[0..7] in fixed order.

constexpr int  C_CLS   = 16;
constexpr long HW      = 512L * 512L;   // 262144 positions per (b,c) plane
constexpr int  BATCH   = 8;
constexpr int  SLAB    = 4096;          // positions per block
constexpr int  SLABS   = (int)(HW / SLAB);   // 64 per batch
constexpr int  NBLK    = BATCH * SLABS;      // 512
constexpr int  NPART   = 3 * C_CLS;          // 48 components

// Full wave64 sum via DPP (rocPRIM pattern). Result valid in lane 63.
__device__ __forceinline__ float wave_reduce_dpp(float x) {
    int t;
    t = __builtin_amdgcn_update_dpp(0, __float_as_int(x), 0x111, 0xf, 0xf, true); // row_shr:1
    x += __int_as_float(t);
    t = __builtin_amdgcn_update_dpp(0, __float_as_int(x), 0x112, 0xf, 0xf, true); // row_shr:2
    x += __int_as_float(t);
    t = __builtin_amdgcn_update_dpp(0, __float_as_int(x), 0x114, 0xf, 0xf, true); // row_shr:4
    x += __int_as_float(t);
    t = __builtin_amdgcn_update_dpp(0, __float_as_int(x), 0x118, 0xf, 0xf, true); // row_shr:8
    x += __int_as_float(t);
    t = __builtin_amdgcn_update_dpp(0, __float_as_int(x), 0x142, 0xa, 0xf, true); // row_bcast:15
    x += __int_as_float(t);
    t = __builtin_amdgcn_update_dpp(0, __float_as_int(x), 0x143, 0xc, 0xf, true); // row_bcast:31
    x += __int_as_float(t);
    return x;
}

__global__ __launch_bounds__(256, 8)
void dice_fused_kernel(const float* __restrict__ pred,
                       const int*   __restrict__ tgt,
                       float*       __restrict__ partial,
                       unsigned*    __restrict__ ctr,
                       float*       __restrict__ out) {
    const int g    = blockIdx.x;
    const int slab = g & (SLABS - 1);
    const int b    = g >> 6;
    const int tid  = threadIdx.x;
    const int lane = tid & 63;
    const int wv   = tid >> 6;

    const long sbase = (long)slab * SLAB;        // within plane
    const int* tb = tgt + (long)b * HW + sbase;

    // pack this thread's 16 target values into one u64 (4 bits each)
    unsigned long long tpack = 0ull;
#pragma unroll
    for (int j = 0; j < 4; ++j) {
        const int4 tv = *reinterpret_cast<const int4*>(tb + j * 1024 + tid * 4);
        const unsigned nib = (unsigned)tv.x | ((unsigned)tv.y << 4)
                           | ((unsigned)tv.z << 8) | ((unsigned)tv.w << 12);
        tpack |= (unsigned long long)nib << (16 * j);
    }

    const float* pb = pred + (long)b * C_CLS * HW + sbase;

    __shared__ float sm[4][NPART];

#pragma unroll
    for (int c = 0; c < C_CLS; ++c) {
        // exact per-nibble (t==c) mask: bit 4i of m = match at position i
        unsigned long long x = tpack ^ ((unsigned long long)c * 0x1111111111111111ull);
        x |= x >> 2;
        x |= x >> 1;
        const unsigned long long m = ~x & 0x1111111111111111ull;

        float isum = 0.f, ov = 0.f;
#pragma unroll
        for (int j = 0; j < 4; ++j) {
            const float4 p = *reinterpret_cast<const float4*>(
                pb + (long)c * HW + j * 1024 + tid * 4);
            const unsigned mb = (unsigned)(m >> (16 * j));
            isum += (p.x + p.y) + (p.z + p.w);
            ov   += ((mb & 0x0001u) ? p.x : 0.f) + ((mb & 0x0010u) ? p.y : 0.f)
                  + ((mb & 0x0100u) ? p.z : 0.f) + ((mb & 0x1000u) ? p.w : 0.f);
        }
        float cntf = (float)__popcll(m);

        isum = wave_reduce_dpp(isum);
        ov   = wave_reduce_dpp(ov);
        cntf = wave_reduce_dpp(cntf);
        if (lane == 63) {
            sm[wv][c * 3 + 0] = isum;
            sm[wv][c * 3 + 1] = ov;
            sm[wv][c * 3 + 2] = cntf;
        }
    }

    __syncthreads();
    if (tid < NPART) {
        // component-major layout: partial[comp][block] for coalesced tail reads
        partial[(long)tid * NBLK + g] =
            (sm[0][tid] + sm[1][tid]) + (sm[2][tid] + sm[3][tid]);
    }
    __threadfence();                       // publish partials device-wide
    __syncthreads();

    __shared__ bool lastf;
    if (tid == 0) lastf = (atomicAdd(ctr, 1u) == (unsigned)(NBLK - 1));
    __syncthreads();
    if (!lastf) return;

    // ---- last-done block: final reduction (fixed order, deterministic) ----
    __threadfence();                       // acquire all partials

    __shared__ float tot[BATCH][NPART];
    // wave wv handles batches 2*wv and 2*wv+1; 64 slab-columns per lane
#pragma unroll
    for (int i = 0; i < 2; ++i) {
        const int bb = wv * 2 + i;
#pragma unroll
        for (int k = 0; k < NPART; ++k) {
            float v = partial[(long)k * NBLK + bb * SLABS + lane];
            v = wave_reduce_dpp(v);
            if (lane == 63) tot[bb][k] = v;
        }
    }
    __syncthreads();

    if (tid < BATCH) {
        float s = 0.f;
#pragma unroll
        for (int c = 0; c < C_CLS; ++c) {
            const float is = tot[tid][c * 3 + 0];
            const float o  = tot[tid][c * 3 + 1];
            const float cn = tot[tid][c * 3 + 2];
            s += (2.f * o + 1.f) / (is + cn + 1.f);
        }
        out[tid] = -s * (1.f / (float)C_CLS);
    }
}

extern "C" void kernel_launch(void* const* d_in, const int* in_sizes, int n_in,
                              void* d_out, int out_size, void* d_ws, size_t ws_size,
                              hipStream_t stream) {
    const float* pred = (const float*)d_in[0];
    const int*   tgt  = (const int*)d_in[1];
    float*       out  = (float*)d_out;

    float*    partial = (float*)d_ws;                       // 48*512*4 = 98304 B
    unsigned* ctr     = (unsigned*)((char*)d_ws + (size_t)NPART * NBLK * 4);

    hipMemsetAsync(ctr, 0, sizeof(unsigned), stream);       // deterministic re-arm
    dice_fused_kernel<<<NBLK, 256, 0, stream>>>(pred, tgt, partial, ctr, out);
}

// Round 13
// 28.738 us; speedup vs baseline: 3.9545x; 3.9545x over previous
//
#include <hip/hip_runtime.h>

// SoftDiceLoss: predictions [B=8, C=16, H=512, W=512] fp32, targets [B,H,W] int32.
// out[b] = -(1/C) * sum_c (2*overlap[b,c] + 1) / (i_sum[b,c] + count[b,c] + 1)
//
// R7 structure VERBATIM — best measured (28.8 us). Five later experiments
// (R8 half-burst, R9/R10 hoisted reductions, R11 manual double-buffer,
// R12 fused last-block tail) ALL regressed by perturbing the compiler's
// scheduling of the main loop (VGPR collapse / scratch spill). Do not touch
// the loop.
//
// Stage 1: 512 blocks = (8 batches x 64 slabs of 4096 positions) x 256 thr.
//   Each thread owns 16 positions; targets packed 4 bits each into ONE u64
//   (tpack). The 16 pred class-segments stream SEQUENTIALLY (contiguous
//   16 KB stream, 4 float4 in flight per thread). Per class: 5-VALU exact
//   nibble==c mask on tpack; count = popcount. Wave reduction uses DPP
//   row_shr/row_bcast (pure VALU, zero DS ops) -> lane 63 -> LDS ->
//   partial[comp][block] in d_ws.
// Stage 2: 8 blocks x 64 threads: thread t reduces one slab-column,
//   lane 63 computes the 16 fracs and writes out[b].

constexpr int  C_CLS   = 16;
constexpr long HW      = 512L * 512L;   // 262144 positions per (b,c) plane
constexpr int  BATCH   = 8;
constexpr int  SLAB    = 4096;          // positions per block
constexpr int  SLABS   = (int)(HW / SLAB);   // 64 per batch
constexpr int  NBLK    = BATCH * SLABS;      // 512
constexpr int  NPART   = 3 * C_CLS;          // 48 components

// Full wave64 sum via DPP (rocPRIM pattern). Result valid in lane 63.
__device__ __forceinline__ float wave_reduce_dpp(float x) {
    int t;
    t = __builtin_amdgcn_update_dpp(0, __float_as_int(x), 0x111, 0xf, 0xf, true); // row_shr:1
    x += __int_as_float(t);
    t = __builtin_amdgcn_update_dpp(0, __float_as_int(x), 0x112, 0xf, 0xf, true); // row_shr:2
    x += __int_as_float(t);
    t = __builtin_amdgcn_update_dpp(0, __float_as_int(x), 0x114, 0xf, 0xf, true); // row_shr:4
    x += __int_as_float(t);
    t = __builtin_amdgcn_update_dpp(0, __float_as_int(x), 0x118, 0xf, 0xf, true); // row_shr:8
    x += __int_as_float(t);
    t = __builtin_amdgcn_update_dpp(0, __float_as_int(x), 0x142, 0xa, 0xf, true); // row_bcast:15
    x += __int_as_float(t);
    t = __builtin_amdgcn_update_dpp(0, __float_as_int(x), 0x143, 0xc, 0xf, true); // row_bcast:31
    x += __int_as_float(t);
    return x;
}

__global__ __launch_bounds__(256, 8)
void dice_partial_kernel(const float* __restrict__ pred,
                         const int*   __restrict__ tgt,
                         float*       __restrict__ partial) {
    const int g    = blockIdx.x;
    const int slab = g & (SLABS - 1);
    const int b    = g >> 6;
    const int tid  = threadIdx.x;
    const int lane = tid & 63;
    const int wv   = tid >> 6;

    const long sbase = (long)slab * SLAB;        // within plane
    const int* tb = tgt + (long)b * HW + sbase;

    // pack this thread's 16 target values into one u64 (4 bits each)
    unsigned long long tpack = 0ull;
#pragma unroll
    for (int j = 0; j < 4; ++j) {
        const int4 tv = *reinterpret_cast<const int4*>(tb + j * 1024 + tid * 4);
        const unsigned nib = (unsigned)tv.x | ((unsigned)tv.y << 4)
                           | ((unsigned)tv.z << 8) | ((unsigned)tv.w << 12);
        tpack |= (unsigned long long)nib << (16 * j);
    }

    const float* pb = pred + (long)b * C_CLS * HW + sbase;

    __shared__ float sm[4][NPART];

#pragma unroll
    for (int c = 0; c < C_CLS; ++c) {
        // exact per-nibble (t==c) mask: bit 4i of m = match at position i
        unsigned long long x = tpack ^ ((unsigned long long)c * 0x1111111111111111ull);
        x |= x >> 2;
        x |= x >> 1;
        const unsigned long long m = ~x & 0x1111111111111111ull;

        float isum = 0.f, ov = 0.f;
#pragma unroll
        for (int j = 0; j < 4; ++j) {
            const float4 p = *reinterpret_cast<const float4*>(
                pb + (long)c * HW + j * 1024 + tid * 4);
            const unsigned mb = (unsigned)(m >> (16 * j));
            isum += (p.x + p.y) + (p.z + p.w);
            ov   += ((mb & 0x0001u) ? p.x : 0.f) + ((mb & 0x0010u) ? p.y : 0.f)
                  + ((mb & 0x0100u) ? p.z : 0.f) + ((mb & 0x1000u) ? p.w : 0.f);
        }
        float cntf = (float)__popcll(m);

        isum = wave_reduce_dpp(isum);
        ov   = wave_reduce_dpp(ov);
        cntf = wave_reduce_dpp(cntf);
        if (lane == 63) {
            sm[wv][c * 3 + 0] = isum;
            sm[wv][c * 3 + 1] = ov;
            sm[wv][c * 3 + 2] = cntf;
        }
    }

    __syncthreads();
    if (tid < NPART) {
        // component-major layout: partial[comp][block] for coalesced stage-2
        partial[(long)tid * NBLK + g] =
            (sm[0][tid] + sm[1][tid]) + (sm[2][tid] + sm[3][tid]);
    }
}

__global__ __launch_bounds__(64)
void dice_final_kernel(const float* __restrict__ partial,
                       float*       __restrict__ out) {
    const int b = blockIdx.x;
    const int t = threadIdx.x;     // one slab-column per lane (64 slabs)

    float acc[NPART];
#pragma unroll
    for (int k = 0; k < NPART; ++k)
        acc[k] = partial[(long)k * NBLK + b * SLABS + t];

#pragma unroll
    for (int k = 0; k < NPART; ++k)
        acc[k] = wave_reduce_dpp(acc[k]);   // totals valid in lane 63

    if (t == 63) {
        float s = 0.f;
#pragma unroll
        for (int c = 0; c < C_CLS; ++c) {
            const float is = acc[c * 3 + 0];
            const float o  = acc[c * 3 + 1];
            const float cn = acc[c * 3 + 2];
            s += (2.f * o + 1.f) / (is + cn + 1.f);
        }
        out[b] = -s * (1.f / (float)C_CLS);
    }
}

extern "C" void kernel_launch(void* const* d_in, const int* in_sizes, int n_in,
                              void* d_out, int out_size, void* d_ws, size_t ws_size,
                              hipStream_t stream) {
    const float* pred = (const float*)d_in[0];
    const int*   tgt  = (const int*)d_in[1];
    float*       out  = (float*)d_out;
    float*       partial = (float*)d_ws;   // 48 * 512 * 4 B = 98304 B

    dice_partial_kernel<<<NBLK, 256, 0, stream>>>(pred, tgt, partial);
    dice_final_kernel<<<BATCH, 64, 0, stream>>>(partial, out);
}